// Round 14
// baseline (158.301 us; speedup 1.0000x reference)
//
#include <hip/hip_runtime.h>
#include <hip/hip_bf16.h>

// ---------------------------------------------------------------------------
// Attention: B=2,N=2048,C=768,H=12,HD=64.  fp32 in/out, f16 MFMA internals.
//   K1: convert x, W_qkv, W_proj fp32 -> f16
//   K2: 128x96-tile GEMM (768 blocks = 3/CU exact; m97-style gl16 staging):
//       qk[token][1536] (q prescaled by (1/8)*log2e); V^T -> vth[bh][64][2048]
//   K3: flash attention, 256 thr/block (4 waves x 32 queries), 32x32x16 MFMA,
//       swapped QK^T, per-og pipeline: QK(og) -> exp+pack+PV(og) fused,
//       XOR-swizzled K/V LDS, double-buffered, 1 barrier/tile, key-split 2,
//       launch_bounds(256,4): cap 128 VGPR -> 4 blocks/CU (was 2)
//   K4: proj GEMM 32x128-tile (768 blocks = 3/CU exact) with fused key-split
//       merge: (O1+O2)/(l1+l2)
// Baseline: R13 measured-best 156.1 us; this round = K3 occupancy only.
// ---------------------------------------------------------------------------

typedef _Float16 half8 __attribute__((ext_vector_type(8)));
typedef _Float16 half4_t __attribute__((ext_vector_type(4)));
typedef float floatx4 __attribute__((ext_vector_type(4)));
typedef float floatx16 __attribute__((ext_vector_type(16)));
typedef unsigned int uintx4 __attribute__((ext_vector_type(4)));
typedef unsigned int uintx2 __attribute__((ext_vector_type(2)));

#define SCALE_LOG2E 0.1803368801111204f   // (1/8) * log2(e)

// ws layout in _Float16 elements
constexpr int XH_OFF    = 0;                          // x as f16: 4096*768
constexpr int WQKV_OFF  = XH_OFF + 4096 * 768;        // 3145728
constexpr int WPROJ_OFF = WQKV_OFF + 2304 * 768;      // 4915200
constexpr int QK_OFF    = WPROJ_OFF + 768 * 768;      // 5505024   [token][1536]
constexpr int VTH_OFF   = QK_OFF + 4096 * 1536;       // 11796480  [bh][64][2048]
constexpr int PO_OFF    = VTH_OFF + 24 * 64 * 2048;   // 14942208  [2][24][2048][64]
constexpr int PSTAT_OFF = PO_OFF + 2 * 24 * 2048 * 64;// 21233664  pL: [2][24][2048] fp32

__device__ __forceinline__ void gl16(const _Float16* g, _Float16* l) {
  __builtin_amdgcn_global_load_lds(
      (const __attribute__((address_space(1))) unsigned int*)g,
      (__attribute__((address_space(3))) unsigned int*)l, 16, 0, 0);
}

// ---------------------------------------------------------------- K1: convert
__global__ __launch_bounds__(256) void cvt_all(const float* __restrict__ x,
                                               const float* __restrict__ wqkv,
                                               const float* __restrict__ wproj,
                                               _Float16* __restrict__ ws) {
  constexpr int n1 = 4096 * 768 / 4;
  constexpr int n2 = 2304 * 768 / 4;
  int i = blockIdx.x * 256 + threadIdx.x;
  const float* src; _Float16* dst; int j;
  if (i < n1)           { src = x;     dst = ws + XH_OFF;    j = i; }
  else if (i < n1 + n2) { src = wqkv;  dst = ws + WQKV_OFF;  j = i - n1; }
  else                  { src = wproj; dst = ws + WPROJ_OFF; j = i - n1 - n2; }
  floatx4 f = *(const floatx4*)(src + 4 * j);
  half4_t h;
  h[0] = (_Float16)f[0]; h[1] = (_Float16)f[1];
  h[2] = (_Float16)f[2]; h[3] = (_Float16)f[3];
  *(half4_t*)(dst + 4 * j) = h;
}

// ------------------------------------------- K2: qkv GEMM (M=4096,N=2304,K=768)
// 128x96 tile, 4 waves (2x2), each wave 64x48 via acc[4][3] of 16x16x32.
// Grid 32x24 = 768 blocks = 3/CU exact.
__global__ __launch_bounds__(256) void qkv_gemm(const _Float16* __restrict__ xh,
                                                const _Float16* __restrict__ wh,
                                                const float* __restrict__ bias,
                                                _Float16* __restrict__ qkh,
                                                _Float16* __restrict__ vth) {
  __shared__ __align__(16) _Float16 sA[128 * 64];
  __shared__ __align__(16) _Float16 sB[96 * 64];
  const int tid = threadIdx.x;
  const int nblk = blockIdx.x % 24, mblk = blockIdx.x / 24;
  const int lane = tid & 63, w = tid >> 6;
  const int lane15 = lane & 15, quad = lane >> 4;
  const int lrow = lane >> 3, lchunk = lane & 7;
  const int wq = w >> 1, wn = w & 1;                  // wave grid 2x2

  floatx4 acc[4][3];
#pragma unroll
  for (int mt = 0; mt < 4; ++mt)
#pragma unroll
    for (int nt = 0; nt < 3; ++nt) acc[mt][nt] = (floatx4){0.f, 0.f, 0.f, 0.f};

  for (int kt = 0; kt < 12; ++kt) {
    if (kt) __syncthreads();
#pragma unroll
    for (int i = 0; i < 7; ++i) {                     // 224 rows: 128 A + 96 B
      int g = i * 32 + w * 8;                         // 8-row group, wave-uniform
      if (g < 128)
        gl16(xh + (mblk * 128 + g + lrow) * 768 + kt * 64 + lchunk * 8, sA + g * 64);
      else
        gl16(wh + (nblk * 96 + (g - 128) + lrow) * 768 + kt * 64 + lchunk * 8,
             sB + (g - 128) * 64);
    }
    __syncthreads();
#pragma unroll
    for (int ks = 0; ks < 2; ++ks) {
      half8 af[4], bf[3];
#pragma unroll
      for (int mt = 0; mt < 4; ++mt)
        af[mt] = *(const half8*)(sA + (wq * 64 + mt * 16 + lane15) * 64 + ks * 32 + quad * 8);
#pragma unroll
      for (int nt = 0; nt < 3; ++nt)
        bf[nt] = *(const half8*)(sB + (wn * 48 + nt * 16 + lane15) * 64 + ks * 32 + quad * 8);
#pragma unroll
      for (int mt = 0; mt < 4; ++mt)
#pragma unroll
        for (int nt = 0; nt < 3; ++nt)
          acc[mt][nt] = __builtin_amdgcn_mfma_f32_16x16x32_f16(af[mt], bf[nt], acc[mt][nt], 0, 0, 0);
    }
  }

  const int mbase = mblk * 128 + wq * 64;
#pragma unroll
  for (int nt = 0; nt < 3; ++nt) {
    int cbase = nblk * 96 + wn * 48 + nt * 16;        // wave-uniform
    float bv = bias[cbase + lane15];
    if (cbase < 1536) {                               // q (prescaled), k
      int col = cbase + lane15;
      float sc = (cbase < 768) ? SCALE_LOG2E : 1.0f;
#pragma unroll
      for (int mt = 0; mt < 4; ++mt)
#pragma unroll
        for (int r = 0; r < 4; ++r) {
          int token = mbase + mt * 16 + quad * 4 + r;
          qkh[token * 1536 + col] = (_Float16)((acc[mt][nt][r] + bv) * sc);
        }
    } else {                                          // v -> vth[bh][d][n]
      int dcol = cbase - 1536 + lane15;               // 16-col group: h uniform
      int h = dcol >> 6, d = dcol & 63;
#pragma unroll
      for (int mt = 0; mt < 4; ++mt) {
        int tok0 = mbase + mt * 16 + quad * 4;
        int b = tok0 >> 11, n0 = tok0 & 2047;
        int bh = b * 12 + h;
        half4_t hv;
#pragma unroll
        for (int r = 0; r < 4; ++r) hv[r] = (_Float16)(acc[mt][nt][r] + bv);
        *(half4_t*)(vth + (bh * 64 + d) * 2048 + n0) = hv;
      }
    }
  }
}

// ---------------------------------------------------------------- K3: attention
// 256 threads = 4 waves, each wave 32 queries x key-half via 32x32x16 MFMA.
// Per-og pipeline: QK^T for 32 keys -> fused exp2+pack -> PV, then next og.
// S^T = mfma(K, Q): col=lane&31=query -> softmax row-sum is lane-local.
// launch_bounds(256,4): cap VGPR at 128 -> 4 waves/SIMD -> 4 blocks/CU.
__global__ __launch_bounds__(256, 4) void attn_fused(const _Float16* __restrict__ qkh,
                                                     const _Float16* __restrict__ vth,
                                                     _Float16* __restrict__ pO,
                                                     float* __restrict__ pL) {
  __shared__ __align__(16) _Float16 sK[2][64 * 64];   // [key][d], swizzled
  __shared__ __align__(16) _Float16 sVT[2][64 * 64];  // [d][key], swizzled
  const int tid = threadIdx.x;
  const int bx = blockIdx.x;
  const int bh = bx % 24;
  const int rest = bx / 24;
  const int ks = rest & 1, qt = rest >> 1;
  const int b = bh / 12, h = bh % 12;
  const int lane = tid & 63, w = tid >> 6;           // w in [0,4)
  const int q = lane & 31, hi = lane >> 5;

  const int qkbase = b * 2048 * 1536 + h * 64;
  const int qrow = qt * 128 + w * 32 + q;

  // Q fragments (prescaled by (1/8)*log2e in K2): B-operand of mfma(K,Q).
  half8 qf[4];
#pragma unroll
  for (int c = 0; c < 4; ++c)
    qf[c] = *(const half8*)(qkh + qkbase + qrow * 1536 + c * 16 + hi * 8);

  // staging: thread -> (row srow, 16B chunks sc and sc+4)
  const int srow = tid >> 2, sc = tid & 3;
  const int key0 = ks * 1024;
  const _Float16* kp = qkh + qkbase + 768 + (key0 + srow) * 1536 + sc * 8;
  const _Float16* vp = vth + (bh * 64 + srow) * 2048 + key0 + sc * 8;
  const int sw0 = srow * 64 + ((sc ^ (srow & 7)) * 8);
  const int sw1 = srow * 64 + (((sc + 4) ^ (srow & 7)) * 8);

  floatx16 O[2];
#pragma unroll
  for (int dg = 0; dg < 2; ++dg)
#pragma unroll
    for (int i = 0; i < 16; ++i) O[dg][i] = 0.f;
  float lrow = 0.f;                                   // per-lane partial sum

  // prolog: stage tile 0, load tile 1 into regs
  half8 rk0 = *(const half8*)kp, rk1 = *(const half8*)(kp + 32);
  half8 rv0 = *(const half8*)vp, rv1 = *(const half8*)(vp + 32);
  kp += 64 * 1536; vp += 64;
  { _Float16* nK = &sK[0][0]; _Float16* nV = &sVT[0][0];
    *(half8*)(nK + sw0) = rk0; *(half8*)(nK + sw1) = rk1;
    *(half8*)(nV + sw0) = rv0; *(half8*)(nV + sw1) = rv1; }
  rk0 = *(const half8*)kp; rk1 = *(const half8*)(kp + 32);
  rv0 = *(const half8*)vp; rv1 = *(const half8*)(vp + 32);
  kp += 64 * 1536; vp += 64;

  for (int kt = 0; kt < 16; ++kt) {
    __syncthreads();   // prev writes of buf[kt&1] visible; prev reads of buf[(kt+1)&1] done
    const _Float16* cK = &sK[kt & 1][0];
    const _Float16* cV = &sVT[kt & 1][0];
    if (kt < 15) {                                    // write tile kt+1 (regs loaded last iter)
      _Float16* nK = &sK[(kt + 1) & 1][0];
      _Float16* nV = &sVT[(kt + 1) & 1][0];
      *(half8*)(nK + sw0) = rk0; *(half8*)(nK + sw1) = rk1;
      *(half8*)(nV + sw0) = rv0; *(half8*)(nV + sw1) = rv1;
      if (kt < 14) {                                  // issue loads for tile kt+2
        rk0 = *(const half8*)kp; rk1 = *(const half8*)(kp + 32);
        rv0 = *(const half8*)vp; rv1 = *(const half8*)(vp + 32);
        kp += 64 * 1536; vp += 64;
      }
    }

    float rsum = 0.f;
#pragma unroll
    for (int og = 0; og < 2; ++og) {
      // S^T[key][q] for 32 keys (one 32x32 output), chained over d (K=16 x4)
      floatx16 s;
#pragma unroll
      for (int i = 0; i < 16; ++i) s[i] = 0.f;
      const int krow = og * 32 + q;
#pragma unroll
      for (int c = 0; c < 4; ++c) {
        half8 kf = *(const half8*)(cK + krow * 64 + (((c * 2 + hi) ^ (krow & 7)) * 8));
        s = __builtin_amdgcn_mfma_f32_32x32x16_f16(kf, qf[c], s, 0, 0, 0);
      }

      // fused softmax+pack+PV per 16-key chunk: m = og*2 + mm
#pragma unroll
      for (int mm = 0; mm < 2; ++mm) {
        const int rb = mm * 8;
        float e0 = __builtin_amdgcn_exp2f(s[rb + 0]);
        float e1 = __builtin_amdgcn_exp2f(s[rb + 1]);
        float e2 = __builtin_amdgcn_exp2f(s[rb + 2]);
        float e3 = __builtin_amdgcn_exp2f(s[rb + 3]);
        float e4 = __builtin_amdgcn_exp2f(s[rb + 4]);
        float e5 = __builtin_amdgcn_exp2f(s[rb + 5]);
        float e6 = __builtin_amdgcn_exp2f(s[rb + 6]);
        float e7 = __builtin_amdgcn_exp2f(s[rb + 7]);
        rsum += ((e0 + e1) + (e2 + e3)) + ((e4 + e5) + (e6 + e7));
        unsigned ua = __builtin_bit_cast(unsigned, __builtin_amdgcn_cvt_pkrtz(e0, e1));
        unsigned ub = __builtin_bit_cast(unsigned, __builtin_amdgcn_cvt_pkrtz(e2, e3));
        unsigned uc = __builtin_bit_cast(unsigned, __builtin_amdgcn_cvt_pkrtz(e4, e5));
        unsigned ud = __builtin_bit_cast(unsigned, __builtin_amdgcn_cvt_pkrtz(e6, e7));
        uintx2 sAC = __builtin_amdgcn_permlane32_swap(ua, uc, false, false);
        uintx2 sBD = __builtin_amdgcn_permlane32_swap(ub, ud, false, false);
        uintx4 u; u[0] = sAC[0]; u[1] = sBD[0]; u[2] = sAC[1]; u[3] = sBD[1];
        half8 bfrag = __builtin_bit_cast(half8, u);

        const int rc2 = (og * 2 + mm) * 2 + hi;
#pragma unroll
        for (int dg = 0; dg < 2; ++dg) {
          const int vrow = dg * 32 + q;
          half8 vf = *(const half8*)(cV + vrow * 64 + ((rc2 ^ (vrow & 7)) * 8));
          O[dg] = __builtin_amdgcn_mfma_f32_32x32x16_f16(vf, bfrag, O[dg], 0, 0, 0);
        }
      }
    }
    lrow += rsum;
  }

  // unnormalized partial epilogue: O^T reg (dg, r) -> d = dg*32 + 8*(r>>2) + 4hi + (r&3)
  const int prow = (ks * 24 + bh) * 2048 + qt * 128 + w * 32;
#pragma unroll
  for (int dg = 0; dg < 2; ++dg)
#pragma unroll
    for (int g2 = 0; g2 < 4; ++g2) {
      half4_t hv;
#pragma unroll
      for (int e = 0; e < 4; ++e) hv[e] = (_Float16)O[dg][g2 * 4 + e];
      *(half4_t*)(pO + (prow + q) * 64 + dg * 32 + g2 * 8 + hi * 4) = hv;
    }
  lrow += __shfl_xor(lrow, 32, 64);
  if (lane < 32) pL[prow + lane] = lrow;
}

// ---------------- K4: proj GEMM (M=4096,N=768,K=768) with fused key-split merge
// 32x128 tile: grid 128x6 = 768 blocks = 3/CU exact.
// 4 waves side-by-side in N; each wave 32x32 = acc[2][2] of 16x16.
__global__ __launch_bounds__(256) void proj_gemm(const _Float16* __restrict__ pO,
                                                 const float* __restrict__ pL,
                                                 const _Float16* __restrict__ wh,
                                                 const float* __restrict__ bias,
                                                 float* __restrict__ out) {
  __shared__ __align__(16) _Float16 sA[32 * 72];    // padded (manual writes)
  __shared__ __align__(16) _Float16 sB[128 * 64];   // unpadded (gl16)
  const int tid = threadIdx.x;
  const int nblk = blockIdx.x % 6, mblk = blockIdx.x / 6;
  const int lane = tid & 63, w = tid >> 6;
  const int lane15 = lane & 15, quad = lane >> 4;
  const int lrow = lane >> 3, lchunk = lane & 7;
  const int arow = tid >> 3, achk = tid & 7;        // A-merge: row in [0,32), chunk
  const int tok0 = mblk * 32;
  const int b = tok0 >> 11, tokl = tok0 & 2047;

  floatx4 acc[2][2];
#pragma unroll
  for (int mt = 0; mt < 2; ++mt)
#pragma unroll
    for (int nt = 0; nt < 2; ++nt) acc[mt][nt] = (floatx4){0.f, 0.f, 0.f, 0.f};

  for (int kt = 0; kt < 12; ++kt) {
    const int bh = b * 12 + kt;                     // head == kt
    const int row1 = bh * 2048 + tokl + arow;
    const int row2 = (24 + bh) * 2048 + tokl + arow;
    float f = 1.0f / (pL[row1] + pL[row2]);

    if (kt) __syncthreads();
    // B staging (async, unpadded): 128 rows, 4 gl16/wave
#pragma unroll
    for (int i = 0; i < 4; ++i) {
      int g = w * 32 + 8 * i;
      gl16(wh + (nblk * 128 + g + lrow) * 768 + kt * 64 + lchunk * 8, sB + g * 64);
    }
    // A staging: load both partials, merge, write padded LDS (1 chunk/thread)
    {
      half8 o1 = *(const half8*)(pO + row1 * 64 + achk * 8);
      half8 o2 = *(const half8*)(pO + row2 * 64 + achk * 8);
      half8 o;
#pragma unroll
      for (int e = 0; e < 8; ++e)
        o[e] = (_Float16)(f * ((float)o1[e] + (float)o2[e]));
      *(half8*)(sA + arow * 72 + achk * 8) = o;
    }
    __syncthreads();

#pragma unroll
    for (int ksplit = 0; ksplit < 2; ++ksplit) {
      half8 af[2], bf[2];
#pragma unroll
      for (int mt = 0; mt < 2; ++mt)
        af[mt] = *(const half8*)(sA + (mt * 16 + lane15) * 72 + ksplit * 32 + quad * 8);
#pragma unroll
      for (int nt = 0; nt < 2; ++nt)
        bf[nt] = *(const half8*)(sB + (w * 32 + nt * 16 + lane15) * 64 + ksplit * 32 + quad * 8);
#pragma unroll
      for (int mt = 0; mt < 2; ++mt)
#pragma unroll
        for (int nt = 0; nt < 2; ++nt)
          acc[mt][nt] = __builtin_amdgcn_mfma_f32_16x16x32_f16(af[mt], bf[nt], acc[mt][nt], 0, 0, 0);
    }
  }

  const int mbase = mblk * 32;
#pragma unroll
  for (int nt = 0; nt < 2; ++nt) {
    int col = nblk * 128 + w * 32 + nt * 16 + lane15;
    float bv = bias[col];
#pragma unroll
    for (int mt = 0; mt < 2; ++mt)
#pragma unroll
      for (int r = 0; r < 4; ++r) {
        int token = mbase + mt * 16 + quad * 4 + r;
        out[token * 768 + col] = acc[mt][nt][r] + bv;
      }
  }
}

// ---------------------------------------------------------------- launch
extern "C" void kernel_launch(void* const* d_in, const int* in_sizes, int n_in,
                              void* d_out, int out_size, void* d_ws, size_t ws_size,
                              hipStream_t stream) {
  const float* x     = (const float*)d_in[0];
  // d_in[1] = xpos (unused: rope is None)
  const float* wqkv  = (const float*)d_in[2];
  const float* bqkv  = (const float*)d_in[3];
  const float* wproj = (const float*)d_in[4];
  const float* bproj = (const float*)d_in[5];
  float* out = (float*)d_out;

  _Float16* ws = (_Float16*)d_ws;
  _Float16* xh     = ws + XH_OFF;
  _Float16* wqkvh  = ws + WQKV_OFF;
  _Float16* wprojh = ws + WPROJ_OFF;
  _Float16* qkh    = ws + QK_OFF;
  _Float16* vth    = ws + VTH_OFF;
  _Float16* pO     = ws + PO_OFF;
  float*    pL     = (float*)(ws + PSTAT_OFF);

  constexpr int total_v4 = (4096 * 768 + 2304 * 768 + 768 * 768) / 4;
  cvt_all<<<total_v4 / 256, 256, 0, stream>>>(x, wqkv, wproj, ws);
  qkv_gemm<<<32 * 24, 256, 0, stream>>>(xh, wqkvh, bqkv, qkh, vth);
  attn_fused<<<24 * 32, 256, 0, stream>>>(qkh, vth, pO, pL);
  proj_gemm<<<128 * 6, 256, 0, stream>>>(pO, pL, wprojh, bproj, out);
}

// Round 15
// 158.054 us; speedup vs baseline: 1.0016x; 1.0016x over previous
//
#include <hip/hip_runtime.h>
#include <hip/hip_bf16.h>

// ---------------------------------------------------------------------------
// Attention: B=2,N=2048,C=768,H=12,HD=64.  fp32 in/out, f16 MFMA internals.
//   K1: convert x, W_qkv, W_proj fp32 -> f16
//   K2: 128x96-tile GEMM (768 blocks = 3/CU exact; m97-style gl16 staging):
//       qk[token][1536] (q prescaled by (1/8)*log2e); V^T -> vth[bh][64][2048]
//   K3: flash attention, 256 thr/block (4 waves x 32 queries), 32x32x16 MFMA,
//       swapped QK^T, per-og pipeline: QK(og) -> exp+pack+PV(og) fused,
//       XOR-swizzled K/V LDS, double-buffered, 1 barrier/tile, key-split 2,
//       launch_bounds(256,3)  [R14's (256,4) reverted: -2us]
//   K3b: merge_o: oh[token][768] = (O1+O2)/(l1+l2) once (was 6x inside K4)
//   K4: proj GEMM 32x128-tile, all-gl16 (A = oh rows, stride 768 like B)
// Baseline: R13 measured-best 156.1 us; this round = factor K4's merge out.
// ---------------------------------------------------------------------------

typedef _Float16 half8 __attribute__((ext_vector_type(8)));
typedef _Float16 half4_t __attribute__((ext_vector_type(4)));
typedef float floatx4 __attribute__((ext_vector_type(4)));
typedef float floatx16 __attribute__((ext_vector_type(16)));
typedef unsigned int uintx4 __attribute__((ext_vector_type(4)));
typedef unsigned int uintx2 __attribute__((ext_vector_type(2)));

#define SCALE_LOG2E 0.1803368801111204f   // (1/8) * log2(e)

// ws layout in _Float16 elements
constexpr int XH_OFF    = 0;                          // x as f16: 4096*768
constexpr int WQKV_OFF  = XH_OFF + 4096 * 768;        // 3145728
constexpr int WPROJ_OFF = WQKV_OFF + 2304 * 768;      // 4915200
constexpr int QK_OFF    = WPROJ_OFF + 768 * 768;      // 5505024   [token][1536]
constexpr int VTH_OFF   = QK_OFF + 4096 * 1536;       // 11796480  [bh][64][2048]
constexpr int PO_OFF    = VTH_OFF + 24 * 64 * 2048;   // 14942208  [2][24][2048][64]
constexpr int PSTAT_OFF = PO_OFF + 2 * 24 * 2048 * 64;// 21233664  pL: [2][24][2048] fp32
constexpr int OH_OFF    = PSTAT_OFF + 2 * 24 * 2048 * 2; // 21430272  [4096][768] f16
// total 24576000 f16 = 49.2 MB; ws is ~268 MB (fill dispatch size) -> fits.

__device__ __forceinline__ void gl16(const _Float16* g, _Float16* l) {
  __builtin_amdgcn_global_load_lds(
      (const __attribute__((address_space(1))) unsigned int*)g,
      (__attribute__((address_space(3))) unsigned int*)l, 16, 0, 0);
}

// ---------------------------------------------------------------- K1: convert
__global__ __launch_bounds__(256) void cvt_all(const float* __restrict__ x,
                                               const float* __restrict__ wqkv,
                                               const float* __restrict__ wproj,
                                               _Float16* __restrict__ ws) {
  constexpr int n1 = 4096 * 768 / 4;
  constexpr int n2 = 2304 * 768 / 4;
  int i = blockIdx.x * 256 + threadIdx.x;
  const float* src; _Float16* dst; int j;
  if (i < n1)           { src = x;     dst = ws + XH_OFF;    j = i; }
  else if (i < n1 + n2) { src = wqkv;  dst = ws + WQKV_OFF;  j = i - n1; }
  else                  { src = wproj; dst = ws + WPROJ_OFF; j = i - n1 - n2; }
  floatx4 f = *(const floatx4*)(src + 4 * j);
  half4_t h;
  h[0] = (_Float16)f[0]; h[1] = (_Float16)f[1];
  h[2] = (_Float16)f[2]; h[3] = (_Float16)f[3];
  *(half4_t*)(dst + 4 * j) = h;
}

// ------------------------------------------- K2: qkv GEMM (M=4096,N=2304,K=768)
// 128x96 tile, 4 waves (2x2), each wave 64x48 via acc[4][3] of 16x16x32.
// Grid 32x24 = 768 blocks = 3/CU exact.
__global__ __launch_bounds__(256) void qkv_gemm(const _Float16* __restrict__ xh,
                                                const _Float16* __restrict__ wh,
                                                const float* __restrict__ bias,
                                                _Float16* __restrict__ qkh,
                                                _Float16* __restrict__ vth) {
  __shared__ __align__(16) _Float16 sA[128 * 64];
  __shared__ __align__(16) _Float16 sB[96 * 64];
  const int tid = threadIdx.x;
  const int nblk = blockIdx.x % 24, mblk = blockIdx.x / 24;
  const int lane = tid & 63, w = tid >> 6;
  const int lane15 = lane & 15, quad = lane >> 4;
  const int lrow = lane >> 3, lchunk = lane & 7;
  const int wq = w >> 1, wn = w & 1;                  // wave grid 2x2

  floatx4 acc[4][3];
#pragma unroll
  for (int mt = 0; mt < 4; ++mt)
#pragma unroll
    for (int nt = 0; nt < 3; ++nt) acc[mt][nt] = (floatx4){0.f, 0.f, 0.f, 0.f};

  for (int kt = 0; kt < 12; ++kt) {
    if (kt) __syncthreads();
#pragma unroll
    for (int i = 0; i < 7; ++i) {                     // 224 rows: 128 A + 96 B
      int g = i * 32 + w * 8;                         // 8-row group, wave-uniform
      if (g < 128)
        gl16(xh + (mblk * 128 + g + lrow) * 768 + kt * 64 + lchunk * 8, sA + g * 64);
      else
        gl16(wh + (nblk * 96 + (g - 128) + lrow) * 768 + kt * 64 + lchunk * 8,
             sB + (g - 128) * 64);
    }
    __syncthreads();
#pragma unroll
    for (int ks = 0; ks < 2; ++ks) {
      half8 af[4], bf[3];
#pragma unroll
      for (int mt = 0; mt < 4; ++mt)
        af[mt] = *(const half8*)(sA + (wq * 64 + mt * 16 + lane15) * 64 + ks * 32 + quad * 8);
#pragma unroll
      for (int nt = 0; nt < 3; ++nt)
        bf[nt] = *(const half8*)(sB + (wn * 48 + nt * 16 + lane15) * 64 + ks * 32 + quad * 8);
#pragma unroll
      for (int mt = 0; mt < 4; ++mt)
#pragma unroll
        for (int nt = 0; nt < 3; ++nt)
          acc[mt][nt] = __builtin_amdgcn_mfma_f32_16x16x32_f16(af[mt], bf[nt], acc[mt][nt], 0, 0, 0);
    }
  }

  const int mbase = mblk * 128 + wq * 64;
#pragma unroll
  for (int nt = 0; nt < 3; ++nt) {
    int cbase = nblk * 96 + wn * 48 + nt * 16;        // wave-uniform
    float bv = bias[cbase + lane15];
    if (cbase < 1536) {                               // q (prescaled), k
      int col = cbase + lane15;
      float sc = (cbase < 768) ? SCALE_LOG2E : 1.0f;
#pragma unroll
      for (int mt = 0; mt < 4; ++mt)
#pragma unroll
        for (int r = 0; r < 4; ++r) {
          int token = mbase + mt * 16 + quad * 4 + r;
          qkh[token * 1536 + col] = (_Float16)((acc[mt][nt][r] + bv) * sc);
        }
    } else {                                          // v -> vth[bh][d][n]
      int dcol = cbase - 1536 + lane15;               // 16-col group: h uniform
      int h = dcol >> 6, d = dcol & 63;
#pragma unroll
      for (int mt = 0; mt < 4; ++mt) {
        int tok0 = mbase + mt * 16 + quad * 4;
        int b = tok0 >> 11, n0 = tok0 & 2047;
        int bh = b * 12 + h;
        half4_t hv;
#pragma unroll
        for (int r = 0; r < 4; ++r) hv[r] = (_Float16)(acc[mt][nt][r] + bv);
        *(half4_t*)(vth + (bh * 64 + d) * 2048 + n0) = hv;
      }
    }
  }
}

// ---------------------------------------------------------------- K3: attention
// 256 threads = 4 waves, each wave 32 queries x key-half via 32x32x16 MFMA.
// Per-og pipeline: QK^T for 32 keys -> fused exp2+pack -> PV, then next og.
// S^T = mfma(K, Q): col=lane&31=query -> softmax row-sum is lane-local.
__global__ __launch_bounds__(256, 3) void attn_fused(const _Float16* __restrict__ qkh,
                                                     const _Float16* __restrict__ vth,
                                                     _Float16* __restrict__ pO,
                                                     float* __restrict__ pL) {
  __shared__ __align__(16) _Float16 sK[2][64 * 64];   // [key][d], swizzled
  __shared__ __align__(16) _Float16 sVT[2][64 * 64];  // [d][key], swizzled
  const int tid = threadIdx.x;
  const int bx = blockIdx.x;
  const int bh = bx % 24;
  const int rest = bx / 24;
  const int ks = rest & 1, qt = rest >> 1;
  const int b = bh / 12, h = bh % 12;
  const int lane = tid & 63, w = tid >> 6;           // w in [0,4)
  const int q = lane & 31, hi = lane >> 5;

  const int qkbase = b * 2048 * 1536 + h * 64;
  const int qrow = qt * 128 + w * 32 + q;

  // Q fragments (prescaled by (1/8)*log2e in K2): B-operand of mfma(K,Q).
  half8 qf[4];
#pragma unroll
  for (int c = 0; c < 4; ++c)
    qf[c] = *(const half8*)(qkh + qkbase + qrow * 1536 + c * 16 + hi * 8);

  // staging: thread -> (row srow, 16B chunks sc and sc+4)
  const int srow = tid >> 2, sc = tid & 3;
  const int key0 = ks * 1024;
  const _Float16* kp = qkh + qkbase + 768 + (key0 + srow) * 1536 + sc * 8;
  const _Float16* vp = vth + (bh * 64 + srow) * 2048 + key0 + sc * 8;
  const int sw0 = srow * 64 + ((sc ^ (srow & 7)) * 8);
  const int sw1 = srow * 64 + (((sc + 4) ^ (srow & 7)) * 8);

  floatx16 O[2];
#pragma unroll
  for (int dg = 0; dg < 2; ++dg)
#pragma unroll
    for (int i = 0; i < 16; ++i) O[dg][i] = 0.f;
  float lrow = 0.f;                                   // per-lane partial sum

  // prolog: stage tile 0, load tile 1 into regs
  half8 rk0 = *(const half8*)kp, rk1 = *(const half8*)(kp + 32);
  half8 rv0 = *(const half8*)vp, rv1 = *(const half8*)(vp + 32);
  kp += 64 * 1536; vp += 64;
  { _Float16* nK = &sK[0][0]; _Float16* nV = &sVT[0][0];
    *(half8*)(nK + sw0) = rk0; *(half8*)(nK + sw1) = rk1;
    *(half8*)(nV + sw0) = rv0; *(half8*)(nV + sw1) = rv1; }
  rk0 = *(const half8*)kp; rk1 = *(const half8*)(kp + 32);
  rv0 = *(const half8*)vp; rv1 = *(const half8*)(vp + 32);
  kp += 64 * 1536; vp += 64;

  for (int kt = 0; kt < 16; ++kt) {
    __syncthreads();   // prev writes of buf[kt&1] visible; prev reads of buf[(kt+1)&1] done
    const _Float16* cK = &sK[kt & 1][0];
    const _Float16* cV = &sVT[kt & 1][0];
    if (kt < 15) {                                    // write tile kt+1 (regs loaded last iter)
      _Float16* nK = &sK[(kt + 1) & 1][0];
      _Float16* nV = &sVT[(kt + 1) & 1][0];
      *(half8*)(nK + sw0) = rk0; *(half8*)(nK + sw1) = rk1;
      *(half8*)(nV + sw0) = rv0; *(half8*)(nV + sw1) = rv1;
      if (kt < 14) {                                  // issue loads for tile kt+2
        rk0 = *(const half8*)kp; rk1 = *(const half8*)(kp + 32);
        rv0 = *(const half8*)vp; rv1 = *(const half8*)(vp + 32);
        kp += 64 * 1536; vp += 64;
      }
    }

    float rsum = 0.f;
#pragma unroll
    for (int og = 0; og < 2; ++og) {
      // S^T[key][q] for 32 keys (one 32x32 output), chained over d (K=16 x4)
      floatx16 s;
#pragma unroll
      for (int i = 0; i < 16; ++i) s[i] = 0.f;
      const int krow = og * 32 + q;
#pragma unroll
      for (int c = 0; c < 4; ++c) {
        half8 kf = *(const half8*)(cK + krow * 64 + (((c * 2 + hi) ^ (krow & 7)) * 8));
        s = __builtin_amdgcn_mfma_f32_32x32x16_f16(kf, qf[c], s, 0, 0, 0);
      }

      // fused softmax+pack+PV per 16-key chunk: m = og*2 + mm
#pragma unroll
      for (int mm = 0; mm < 2; ++mm) {
        const int rb = mm * 8;
        float e0 = __builtin_amdgcn_exp2f(s[rb + 0]);
        float e1 = __builtin_amdgcn_exp2f(s[rb + 1]);
        float e2 = __builtin_amdgcn_exp2f(s[rb + 2]);
        float e3 = __builtin_amdgcn_exp2f(s[rb + 3]);
        float e4 = __builtin_amdgcn_exp2f(s[rb + 4]);
        float e5 = __builtin_amdgcn_exp2f(s[rb + 5]);
        float e6 = __builtin_amdgcn_exp2f(s[rb + 6]);
        float e7 = __builtin_amdgcn_exp2f(s[rb + 7]);
        rsum += ((e0 + e1) + (e2 + e3)) + ((e4 + e5) + (e6 + e7));
        unsigned ua = __builtin_bit_cast(unsigned, __builtin_amdgcn_cvt_pkrtz(e0, e1));
        unsigned ub = __builtin_bit_cast(unsigned, __builtin_amdgcn_cvt_pkrtz(e2, e3));
        unsigned uc = __builtin_bit_cast(unsigned, __builtin_amdgcn_cvt_pkrtz(e4, e5));
        unsigned ud = __builtin_bit_cast(unsigned, __builtin_amdgcn_cvt_pkrtz(e6, e7));
        uintx2 sAC = __builtin_amdgcn_permlane32_swap(ua, uc, false, false);
        uintx2 sBD = __builtin_amdgcn_permlane32_swap(ub, ud, false, false);
        uintx4 u; u[0] = sAC[0]; u[1] = sBD[0]; u[2] = sAC[1]; u[3] = sBD[1];
        half8 bfrag = __builtin_bit_cast(half8, u);

        const int rc2 = (og * 2 + mm) * 2 + hi;
#pragma unroll
        for (int dg = 0; dg < 2; ++dg) {
          const int vrow = dg * 32 + q;
          half8 vf = *(const half8*)(cV + vrow * 64 + ((rc2 ^ (vrow & 7)) * 8));
          O[dg] = __builtin_amdgcn_mfma_f32_32x32x16_f16(vf, bfrag, O[dg], 0, 0, 0);
        }
      }
    }
    lrow += rsum;
  }

  // unnormalized partial epilogue: O^T reg (dg, r) -> d = dg*32 + 8*(r>>2) + 4hi + (r&3)
  const int prow = (ks * 24 + bh) * 2048 + qt * 128 + w * 32;
#pragma unroll
  for (int dg = 0; dg < 2; ++dg)
#pragma unroll
    for (int g2 = 0; g2 < 4; ++g2) {
      half4_t hv;
#pragma unroll
      for (int e = 0; e < 4; ++e) hv[e] = (_Float16)O[dg][g2 * 4 + e];
      *(half4_t*)(pO + (prow + q) * 64 + dg * 32 + g2 * 8 + hi * 4) = hv;
    }
  lrow += __shfl_xor(lrow, 32, 64);
  if (lane < 32) pL[prow + lane] = lrow;
}

// ------------------------------------------- K3b: merge key-split partials once
// oh[token][h*64+d] = (pO[ks=0] + pO[ks=1]) / (l1+l2).  half8 per thread.
__global__ __launch_bounds__(256) void merge_o(const _Float16* __restrict__ pO,
                                               const float* __restrict__ pL,
                                               _Float16* __restrict__ oh) {
  int i = blockIdx.x * 256 + threadIdx.x;             // 393216 threads
  int token = i / 96, c = i % 96;                     // c: 8-dim chunk in [0,96)
  int h = c >> 3, d0 = (c & 7) * 8;
  int b = token >> 11, n = token & 2047;
  int bh = b * 12 + h;
  int row1 = bh * 2048 + n;
  int row2 = (24 + bh) * 2048 + n;
  float f = 1.0f / (pL[row1] + pL[row2]);
  half8 o1 = *(const half8*)(pO + row1 * 64 + d0);
  half8 o2 = *(const half8*)(pO + row2 * 64 + d0);
  half8 o;
#pragma unroll
  for (int e = 0; e < 8; ++e)
    o[e] = (_Float16)(f * ((float)o1[e] + (float)o2[e]));
  *(half8*)(oh + token * 768 + c * 8) = o;
}

// ---------------- K4: proj GEMM (M=4096,N=768,K=768), A = oh (normalized f16)
// 32x128 tile: grid 128x6 = 768 blocks = 3/CU exact.  All-gl16 staging
// (A rows stride 768 exactly like B).  4 waves side-by-side in N; each wave
// 32x32 = acc[2][2] of 16x16.  Single-buffered (2 barriers/kt), as R13.
__global__ __launch_bounds__(256) void proj_gemm(const _Float16* __restrict__ oh,
                                                 const _Float16* __restrict__ wh,
                                                 const float* __restrict__ bias,
                                                 float* __restrict__ out) {
  __shared__ __align__(16) _Float16 sA[32 * 64];    // unpadded (gl16)
  __shared__ __align__(16) _Float16 sB[128 * 64];   // unpadded (gl16)
  const int tid = threadIdx.x;
  const int nblk = blockIdx.x % 6, mblk = blockIdx.x / 6;
  const int lane = tid & 63, w = tid >> 6;
  const int lane15 = lane & 15, quad = lane >> 4;
  const int lrow = lane >> 3, lchunk = lane & 7;

  floatx4 acc[2][2];
#pragma unroll
  for (int mt = 0; mt < 2; ++mt)
#pragma unroll
    for (int nt = 0; nt < 2; ++nt) acc[mt][nt] = (floatx4){0.f, 0.f, 0.f, 0.f};

  for (int kt = 0; kt < 12; ++kt) {
    if (kt) __syncthreads();
    // B staging: 128 rows, 4 gl16/wave
#pragma unroll
    for (int i = 0; i < 4; ++i) {
      int g = w * 32 + 8 * i;
      gl16(wh + (nblk * 128 + g + lrow) * 768 + kt * 64 + lchunk * 8, sB + g * 64);
    }
    // A staging: 32 rows, 1 gl16/wave (rows w*8 + lrow)
    gl16(oh + (mblk * 32 + w * 8 + lrow) * 768 + kt * 64 + lchunk * 8,
         sA + (w * 8) * 64);
    __syncthreads();

#pragma unroll
    for (int ksplit = 0; ksplit < 2; ++ksplit) {
      half8 af[2], bf[2];
#pragma unroll
      for (int mt = 0; mt < 2; ++mt)
        af[mt] = *(const half8*)(sA + (mt * 16 + lane15) * 64 + ksplit * 32 + quad * 8);
#pragma unroll
      for (int nt = 0; nt < 2; ++nt)
        bf[nt] = *(const half8*)(sB + (w * 32 + nt * 16 + lane15) * 64 + ksplit * 32 + quad * 8);
#pragma unroll
      for (int mt = 0; mt < 2; ++mt)
#pragma unroll
        for (int nt = 0; nt < 2; ++nt)
          acc[mt][nt] = __builtin_amdgcn_mfma_f32_16x16x32_f16(af[mt], bf[nt], acc[mt][nt], 0, 0, 0);
    }
  }

  const int mbase = mblk * 32;
#pragma unroll
  for (int nt = 0; nt < 2; ++nt) {
    int col = nblk * 128 + w * 32 + nt * 16 + lane15;
    float bv = bias[col];
#pragma unroll
    for (int mt = 0; mt < 2; ++mt)
#pragma unroll
      for (int r = 0; r < 4; ++r) {
        int token = mbase + mt * 16 + quad * 4 + r;
        out[token * 768 + col] = acc[mt][nt][r] + bv;
      }
  }
}

// ---------------------------------------------------------------- launch
extern "C" void kernel_launch(void* const* d_in, const int* in_sizes, int n_in,
                              void* d_out, int out_size, void* d_ws, size_t ws_size,
                              hipStream_t stream) {
  const float* x     = (const float*)d_in[0];
  // d_in[1] = xpos (unused: rope is None)
  const float* wqkv  = (const float*)d_in[2];
  const float* bqkv  = (const float*)d_in[3];
  const float* wproj = (const float*)d_in[4];
  const float* bproj = (const float*)d_in[5];
  float* out = (float*)d_out;

  _Float16* ws = (_Float16*)d_ws;
  _Float16* xh     = ws + XH_OFF;
  _Float16* wqkvh  = ws + WQKV_OFF;
  _Float16* wprojh = ws + WPROJ_OFF;
  _Float16* qkh    = ws + QK_OFF;
  _Float16* vth    = ws + VTH_OFF;
  _Float16* pO     = ws + PO_OFF;
  float*    pL     = (float*)(ws + PSTAT_OFF);
  _Float16* oh     = ws + OH_OFF;

  constexpr int total_v4 = (4096 * 768 + 2304 * 768 + 768 * 768) / 4;
  cvt_all<<<total_v4 / 256, 256, 0, stream>>>(x, wqkv, wproj, ws);
  qkv_gemm<<<32 * 24, 256, 0, stream>>>(xh, wqkvh, bqkv, qkh, vth);
  attn_fused<<<24 * 32, 256, 0, stream>>>(qkh, vth, pO, pL);
  merge_o<<<4096 * 768 / 8 / 256, 256, 0, stream>>>(pO, pL, oh);
  proj_gemm<<<128 * 6, 256, 0, stream>>>(oh, wprojh, bproj, out);
}

// Round 16
// 155.490 us; speedup vs baseline: 1.0181x; 1.0165x over previous
//
#include <hip/hip_runtime.h>
#include <hip/hip_bf16.h>

// ---------------------------------------------------------------------------
// Attention: B=2,N=2048,C=768,H=12,HD=64.  fp32 in/out, f16 MFMA internals.
//   K1: convert x, W_qkv, W_proj fp32 -> f16
//   K2: 128x96-tile GEMM (768 blocks = 3/CU exact; m97-style gl16 staging):
//       qk[token][1536] (q prescaled by (1/8)*log2e); V^T -> vth[bh][64][2048]
//   K3: flash attention, 256 thr/block (4 waves x 32 queries), 32x32x16 MFMA,
//       swapped QK^T, per-og pipeline: QK(og) -> exp+pack+PV(og) fused,
//       XOR-swizzled K/V LDS, double-buffered, 1 barrier/tile, key-split 2,
//       s_setprio(1) around MFMA clusters (T5; cross-block wave diversity)
//   K4: proj GEMM 32x128-tile (768 blocks = 3/CU exact) with fused key-split
//       merge: (O1+O2)/(l1+l2)
// Baseline: R13 measured-best 156.1 us (R14/R15 reverted); +T5 on K3 only.
// ---------------------------------------------------------------------------

typedef _Float16 half8 __attribute__((ext_vector_type(8)));
typedef _Float16 half4_t __attribute__((ext_vector_type(4)));
typedef float floatx4 __attribute__((ext_vector_type(4)));
typedef float floatx16 __attribute__((ext_vector_type(16)));
typedef unsigned int uintx4 __attribute__((ext_vector_type(4)));
typedef unsigned int uintx2 __attribute__((ext_vector_type(2)));

#define SCALE_LOG2E 0.1803368801111204f   // (1/8) * log2(e)

// ws layout in _Float16 elements
constexpr int XH_OFF    = 0;                          // x as f16: 4096*768
constexpr int WQKV_OFF  = XH_OFF + 4096 * 768;        // 3145728
constexpr int WPROJ_OFF = WQKV_OFF + 2304 * 768;      // 4915200
constexpr int QK_OFF    = WPROJ_OFF + 768 * 768;      // 5505024   [token][1536]
constexpr int VTH_OFF   = QK_OFF + 4096 * 1536;       // 11796480  [bh][64][2048]
constexpr int PO_OFF    = VTH_OFF + 24 * 64 * 2048;   // 14942208  [2][24][2048][64]
constexpr int PSTAT_OFF = PO_OFF + 2 * 24 * 2048 * 64;// 21233664  pL: [2][24][2048] fp32

__device__ __forceinline__ void gl16(const _Float16* g, _Float16* l) {
  __builtin_amdgcn_global_load_lds(
      (const __attribute__((address_space(1))) unsigned int*)g,
      (__attribute__((address_space(3))) unsigned int*)l, 16, 0, 0);
}

// ---------------------------------------------------------------- K1: convert
__global__ __launch_bounds__(256) void cvt_all(const float* __restrict__ x,
                                               const float* __restrict__ wqkv,
                                               const float* __restrict__ wproj,
                                               _Float16* __restrict__ ws) {
  constexpr int n1 = 4096 * 768 / 4;
  constexpr int n2 = 2304 * 768 / 4;
  int i = blockIdx.x * 256 + threadIdx.x;
  const float* src; _Float16* dst; int j;
  if (i < n1)           { src = x;     dst = ws + XH_OFF;    j = i; }
  else if (i < n1 + n2) { src = wqkv;  dst = ws + WQKV_OFF;  j = i - n1; }
  else                  { src = wproj; dst = ws + WPROJ_OFF; j = i - n1 - n2; }
  floatx4 f = *(const floatx4*)(src + 4 * j);
  half4_t h;
  h[0] = (_Float16)f[0]; h[1] = (_Float16)f[1];
  h[2] = (_Float16)f[2]; h[3] = (_Float16)f[3];
  *(half4_t*)(dst + 4 * j) = h;
}

// ------------------------------------------- K2: qkv GEMM (M=4096,N=2304,K=768)
// 128x96 tile, 4 waves (2x2), each wave 64x48 via acc[4][3] of 16x16x32.
// Grid 32x24 = 768 blocks = 3/CU exact.
__global__ __launch_bounds__(256) void qkv_gemm(const _Float16* __restrict__ xh,
                                                const _Float16* __restrict__ wh,
                                                const float* __restrict__ bias,
                                                _Float16* __restrict__ qkh,
                                                _Float16* __restrict__ vth) {
  __shared__ __align__(16) _Float16 sA[128 * 64];
  __shared__ __align__(16) _Float16 sB[96 * 64];
  const int tid = threadIdx.x;
  const int nblk = blockIdx.x % 24, mblk = blockIdx.x / 24;
  const int lane = tid & 63, w = tid >> 6;
  const int lane15 = lane & 15, quad = lane >> 4;
  const int lrow = lane >> 3, lchunk = lane & 7;
  const int wq = w >> 1, wn = w & 1;                  // wave grid 2x2

  floatx4 acc[4][3];
#pragma unroll
  for (int mt = 0; mt < 4; ++mt)
#pragma unroll
    for (int nt = 0; nt < 3; ++nt) acc[mt][nt] = (floatx4){0.f, 0.f, 0.f, 0.f};

  for (int kt = 0; kt < 12; ++kt) {
    if (kt) __syncthreads();
#pragma unroll
    for (int i = 0; i < 7; ++i) {                     // 224 rows: 128 A + 96 B
      int g = i * 32 + w * 8;                         // 8-row group, wave-uniform
      if (g < 128)
        gl16(xh + (mblk * 128 + g + lrow) * 768 + kt * 64 + lchunk * 8, sA + g * 64);
      else
        gl16(wh + (nblk * 96 + (g - 128) + lrow) * 768 + kt * 64 + lchunk * 8,
             sB + (g - 128) * 64);
    }
    __syncthreads();
#pragma unroll
    for (int ks = 0; ks < 2; ++ks) {
      half8 af[4], bf[3];
#pragma unroll
      for (int mt = 0; mt < 4; ++mt)
        af[mt] = *(const half8*)(sA + (wq * 64 + mt * 16 + lane15) * 64 + ks * 32 + quad * 8);
#pragma unroll
      for (int nt = 0; nt < 3; ++nt)
        bf[nt] = *(const half8*)(sB + (wn * 48 + nt * 16 + lane15) * 64 + ks * 32 + quad * 8);
#pragma unroll
      for (int mt = 0; mt < 4; ++mt)
#pragma unroll
        for (int nt = 0; nt < 3; ++nt)
          acc[mt][nt] = __builtin_amdgcn_mfma_f32_16x16x32_f16(af[mt], bf[nt], acc[mt][nt], 0, 0, 0);
    }
  }

  const int mbase = mblk * 128 + wq * 64;
#pragma unroll
  for (int nt = 0; nt < 3; ++nt) {
    int cbase = nblk * 96 + wn * 48 + nt * 16;        // wave-uniform
    float bv = bias[cbase + lane15];
    if (cbase < 1536) {                               // q (prescaled), k
      int col = cbase + lane15;
      float sc = (cbase < 768) ? SCALE_LOG2E : 1.0f;
#pragma unroll
      for (int mt = 0; mt < 4; ++mt)
#pragma unroll
        for (int r = 0; r < 4; ++r) {
          int token = mbase + mt * 16 + quad * 4 + r;
          qkh[token * 1536 + col] = (_Float16)((acc[mt][nt][r] + bv) * sc);
        }
    } else {                                          // v -> vth[bh][d][n]
      int dcol = cbase - 1536 + lane15;               // 16-col group: h uniform
      int h = dcol >> 6, d = dcol & 63;
#pragma unroll
      for (int mt = 0; mt < 4; ++mt) {
        int tok0 = mbase + mt * 16 + quad * 4;
        int b = tok0 >> 11, n0 = tok0 & 2047;
        int bh = b * 12 + h;
        half4_t hv;
#pragma unroll
        for (int r = 0; r < 4; ++r) hv[r] = (_Float16)(acc[mt][nt][r] + bv);
        *(half4_t*)(vth + (bh * 64 + d) * 2048 + n0) = hv;
      }
    }
  }
}

// ---------------------------------------------------------------- K3: attention
// 256 threads = 4 waves, each wave 32 queries x key-half via 32x32x16 MFMA.
// Per-og pipeline: QK^T for 32 keys -> fused exp2+pack -> PV, then next og.
// S^T = mfma(K, Q): col=lane&31=query -> softmax row-sum is lane-local.
// T5: setprio(1) around MFMA clusters (3 indep blocks/CU -> wave diversity).
__global__ __launch_bounds__(256, 3) void attn_fused(const _Float16* __restrict__ qkh,
                                                     const _Float16* __restrict__ vth,
                                                     _Float16* __restrict__ pO,
                                                     float* __restrict__ pL) {
  __shared__ __align__(16) _Float16 sK[2][64 * 64];   // [key][d], swizzled
  __shared__ __align__(16) _Float16 sVT[2][64 * 64];  // [d][key], swizzled
  const int tid = threadIdx.x;
  const int bx = blockIdx.x;
  const int bh = bx % 24;
  const int rest = bx / 24;
  const int ks = rest & 1, qt = rest >> 1;
  const int b = bh / 12, h = bh % 12;
  const int lane = tid & 63, w = tid >> 6;           // w in [0,4)
  const int q = lane & 31, hi = lane >> 5;

  const int qkbase = b * 2048 * 1536 + h * 64;
  const int qrow = qt * 128 + w * 32 + q;

  // Q fragments (prescaled by (1/8)*log2e in K2): B-operand of mfma(K,Q).
  half8 qf[4];
#pragma unroll
  for (int c = 0; c < 4; ++c)
    qf[c] = *(const half8*)(qkh + qkbase + qrow * 1536 + c * 16 + hi * 8);

  // staging: thread -> (row srow, 16B chunks sc and sc+4)
  const int srow = tid >> 2, sc = tid & 3;
  const int key0 = ks * 1024;
  const _Float16* kp = qkh + qkbase + 768 + (key0 + srow) * 1536 + sc * 8;
  const _Float16* vp = vth + (bh * 64 + srow) * 2048 + key0 + sc * 8;
  const int sw0 = srow * 64 + ((sc ^ (srow & 7)) * 8);
  const int sw1 = srow * 64 + (((sc + 4) ^ (srow & 7)) * 8);

  floatx16 O[2];
#pragma unroll
  for (int dg = 0; dg < 2; ++dg)
#pragma unroll
    for (int i = 0; i < 16; ++i) O[dg][i] = 0.f;
  float lrow = 0.f;                                   // per-lane partial sum

  // prolog: stage tile 0, load tile 1 into regs
  half8 rk0 = *(const half8*)kp, rk1 = *(const half8*)(kp + 32);
  half8 rv0 = *(const half8*)vp, rv1 = *(const half8*)(vp + 32);
  kp += 64 * 1536; vp += 64;
  { _Float16* nK = &sK[0][0]; _Float16* nV = &sVT[0][0];
    *(half8*)(nK + sw0) = rk0; *(half8*)(nK + sw1) = rk1;
    *(half8*)(nV + sw0) = rv0; *(half8*)(nV + sw1) = rv1; }
  rk0 = *(const half8*)kp; rk1 = *(const half8*)(kp + 32);
  rv0 = *(const half8*)vp; rv1 = *(const half8*)(vp + 32);
  kp += 64 * 1536; vp += 64;

  for (int kt = 0; kt < 16; ++kt) {
    __syncthreads();   // prev writes of buf[kt&1] visible; prev reads of buf[(kt+1)&1] done
    const _Float16* cK = &sK[kt & 1][0];
    const _Float16* cV = &sVT[kt & 1][0];
    if (kt < 15) {                                    // write tile kt+1 (regs loaded last iter)
      _Float16* nK = &sK[(kt + 1) & 1][0];
      _Float16* nV = &sVT[(kt + 1) & 1][0];
      *(half8*)(nK + sw0) = rk0; *(half8*)(nK + sw1) = rk1;
      *(half8*)(nV + sw0) = rv0; *(half8*)(nV + sw1) = rv1;
      if (kt < 14) {                                  // issue loads for tile kt+2
        rk0 = *(const half8*)kp; rk1 = *(const half8*)(kp + 32);
        rv0 = *(const half8*)vp; rv1 = *(const half8*)(vp + 32);
        kp += 64 * 1536; vp += 64;
      }
    }

    float rsum = 0.f;
#pragma unroll
    for (int og = 0; og < 2; ++og) {
      // S^T[key][q] for 32 keys (one 32x32 output), chained over d (K=16 x4)
      floatx16 s;
#pragma unroll
      for (int i = 0; i < 16; ++i) s[i] = 0.f;
      const int krow = og * 32 + q;
      __builtin_amdgcn_s_setprio(1);
#pragma unroll
      for (int c = 0; c < 4; ++c) {
        half8 kf = *(const half8*)(cK + krow * 64 + (((c * 2 + hi) ^ (krow & 7)) * 8));
        s = __builtin_amdgcn_mfma_f32_32x32x16_f16(kf, qf[c], s, 0, 0, 0);
      }
      __builtin_amdgcn_s_setprio(0);

      // fused softmax+pack+PV per 16-key chunk: m = og*2 + mm
#pragma unroll
      for (int mm = 0; mm < 2; ++mm) {
        const int rb = mm * 8;
        float e0 = __builtin_amdgcn_exp2f(s[rb + 0]);
        float e1 = __builtin_amdgcn_exp2f(s[rb + 1]);
        float e2 = __builtin_amdgcn_exp2f(s[rb + 2]);
        float e3 = __builtin_amdgcn_exp2f(s[rb + 3]);
        float e4 = __builtin_amdgcn_exp2f(s[rb + 4]);
        float e5 = __builtin_amdgcn_exp2f(s[rb + 5]);
        float e6 = __builtin_amdgcn_exp2f(s[rb + 6]);
        float e7 = __builtin_amdgcn_exp2f(s[rb + 7]);
        rsum += ((e0 + e1) + (e2 + e3)) + ((e4 + e5) + (e6 + e7));
        unsigned ua = __builtin_bit_cast(unsigned, __builtin_amdgcn_cvt_pkrtz(e0, e1));
        unsigned ub = __builtin_bit_cast(unsigned, __builtin_amdgcn_cvt_pkrtz(e2, e3));
        unsigned uc = __builtin_bit_cast(unsigned, __builtin_amdgcn_cvt_pkrtz(e4, e5));
        unsigned ud = __builtin_bit_cast(unsigned, __builtin_amdgcn_cvt_pkrtz(e6, e7));
        uintx2 sAC = __builtin_amdgcn_permlane32_swap(ua, uc, false, false);
        uintx2 sBD = __builtin_amdgcn_permlane32_swap(ub, ud, false, false);
        uintx4 u; u[0] = sAC[0]; u[1] = sBD[0]; u[2] = sAC[1]; u[3] = sBD[1];
        half8 bfrag = __builtin_bit_cast(half8, u);

        const int rc2 = (og * 2 + mm) * 2 + hi;
        __builtin_amdgcn_s_setprio(1);
#pragma unroll
        for (int dg = 0; dg < 2; ++dg) {
          const int vrow = dg * 32 + q;
          half8 vf = *(const half8*)(cV + vrow * 64 + ((rc2 ^ (vrow & 7)) * 8));
          O[dg] = __builtin_amdgcn_mfma_f32_32x32x16_f16(vf, bfrag, O[dg], 0, 0, 0);
        }
        __builtin_amdgcn_s_setprio(0);
      }
    }
    lrow += rsum;
  }

  // unnormalized partial epilogue: O^T reg (dg, r) -> d = dg*32 + 8*(r>>2) + 4hi + (r&3)
  const int prow = (ks * 24 + bh) * 2048 + qt * 128 + w * 32;
#pragma unroll
  for (int dg = 0; dg < 2; ++dg)
#pragma unroll
    for (int g2 = 0; g2 < 4; ++g2) {
      half4_t hv;
#pragma unroll
      for (int e = 0; e < 4; ++e) hv[e] = (_Float16)O[dg][g2 * 4 + e];
      *(half4_t*)(pO + (prow + q) * 64 + dg * 32 + g2 * 8 + hi * 4) = hv;
    }
  lrow += __shfl_xor(lrow, 32, 64);
  if (lane < 32) pL[prow + lane] = lrow;
}

// ---------------- K4: proj GEMM (M=4096,N=768,K=768) with fused key-split merge
// 32x128 tile: grid 128x6 = 768 blocks = 3/CU exact.
// 4 waves side-by-side in N; each wave 32x32 = acc[2][2] of 16x16.
__global__ __launch_bounds__(256) void proj_gemm(const _Float16* __restrict__ pO,
                                                 const float* __restrict__ pL,
                                                 const _Float16* __restrict__ wh,
                                                 const float* __restrict__ bias,
                                                 float* __restrict__ out) {
  __shared__ __align__(16) _Float16 sA[32 * 72];    // padded (manual writes)
  __shared__ __align__(16) _Float16 sB[128 * 64];   // unpadded (gl16)
  const int tid = threadIdx.x;
  const int nblk = blockIdx.x % 6, mblk = blockIdx.x / 6;
  const int lane = tid & 63, w = tid >> 6;
  const int lane15 = lane & 15, quad = lane >> 4;
  const int lrow = lane >> 3, lchunk = lane & 7;
  const int arow = tid >> 3, achk = tid & 7;        // A-merge: row in [0,32), chunk
  const int tok0 = mblk * 32;
  const int b = tok0 >> 11, tokl = tok0 & 2047;

  floatx4 acc[2][2];
#pragma unroll
  for (int mt = 0; mt < 2; ++mt)
#pragma unroll
    for (int nt = 0; nt < 2; ++nt) acc[mt][nt] = (floatx4){0.f, 0.f, 0.f, 0.f};

  for (int kt = 0; kt < 12; ++kt) {
    const int bh = b * 12 + kt;                     // head == kt
    const int row1 = bh * 2048 + tokl + arow;
    const int row2 = (24 + bh) * 2048 + tokl + arow;
    float f = 1.0f / (pL[row1] + pL[row2]);

    if (kt) __syncthreads();
    // B staging (async, unpadded): 128 rows, 4 gl16/wave
#pragma unroll
    for (int i = 0; i < 4; ++i) {
      int g = w * 32 + 8 * i;
      gl16(wh + (nblk * 128 + g + lrow) * 768 + kt * 64 + lchunk * 8, sB + g * 64);
    }
    // A staging: load both partials, merge, write padded LDS (1 chunk/thread)
    {
      half8 o1 = *(const half8*)(pO + row1 * 64 + achk * 8);
      half8 o2 = *(const half8*)(pO + row2 * 64 + achk * 8);
      half8 o;
#pragma unroll
      for (int e = 0; e < 8; ++e)
        o[e] = (_Float16)(f * ((float)o1[e] + (float)o2[e]));
      *(half8*)(sA + arow * 72 + achk * 8) = o;
    }
    __syncthreads();

#pragma unroll
    for (int ksplit = 0; ksplit < 2; ++ksplit) {
      half8 af[2], bf[2];
#pragma unroll
      for (int mt = 0; mt < 2; ++mt)
        af[mt] = *(const half8*)(sA + (mt * 16 + lane15) * 72 + ksplit * 32 + quad * 8);
#pragma unroll
      for (int nt = 0; nt < 2; ++nt)
        bf[nt] = *(const half8*)(sB + (w * 32 + nt * 16 + lane15) * 64 + ksplit * 32 + quad * 8);
#pragma unroll
      for (int mt = 0; mt < 2; ++mt)
#pragma unroll
        for (int nt = 0; nt < 2; ++nt)
          acc[mt][nt] = __builtin_amdgcn_mfma_f32_16x16x32_f16(af[mt], bf[nt], acc[mt][nt], 0, 0, 0);
    }
  }

  const int mbase = mblk * 32;
#pragma unroll
  for (int nt = 0; nt < 2; ++nt) {
    int col = nblk * 128 + w * 32 + nt * 16 + lane15;
    float bv = bias[col];
#pragma unroll
    for (int mt = 0; mt < 2; ++mt)
#pragma unroll
      for (int r = 0; r < 4; ++r) {
        int token = mbase + mt * 16 + quad * 4 + r;
        out[token * 768 + col] = acc[mt][nt][r] + bv;
      }
  }
}

// ---------------------------------------------------------------- launch
extern "C" void kernel_launch(void* const* d_in, const int* in_sizes, int n_in,
                              void* d_out, int out_size, void* d_ws, size_t ws_size,
                              hipStream_t stream) {
  const float* x     = (const float*)d_in[0];
  // d_in[1] = xpos (unused: rope is None)
  const float* wqkv  = (const float*)d_in[2];
  const float* bqkv  = (const float*)d_in[3];
  const float* wproj = (const float*)d_in[4];
  const float* bproj = (const float*)d_in[5];
  float* out = (float*)d_out;

  _Float16* ws = (_Float16*)d_ws;
  _Float16* xh     = ws + XH_OFF;
  _Float16* wqkvh  = ws + WQKV_OFF;
  _Float16* wprojh = ws + WPROJ_OFF;
  _Float16* qkh    = ws + QK_OFF;
  _Float16* vth    = ws + VTH_OFF;
  _Float16* pO     = ws + PO_OFF;
  float*    pL     = (float*)(ws + PSTAT_OFF);

  constexpr int total_v4 = (4096 * 768 + 2304 * 768 + 768 * 768) / 4;
  cvt_all<<<total_v4 / 256, 256, 0, stream>>>(x, wqkv, wproj, ws);
  qkv_gemm<<<32 * 24, 256, 0, stream>>>(xh, wqkvh, bqkv, qkh, vth);
  attn_fused<<<24 * 32, 256, 0, stream>>>(qkh, vth, pO, pL);
  proj_gemm<<<128 * 6, 256, 0, stream>>>(pO, pL, wprojh, bproj, out);
}